// Round 18
// baseline (380.005 us; speedup 1.0000x reference)
//
#include <hip/hip_runtime.h>
#include <hip/hip_bf16.h>

// x [B=2, C=16, T=31, H=256, W=256] fp32
#define TDIM 31
#define TS   65536                 // t stride (H*W)
#define CS   (TDIM * TS)           // c stride = 2,031,616
#define BS   (16 * CS)             // b stride
#define NTOT (2 * BS)              // 65,011,712
#define GAP_INV (1.0f / (31.0f * 65536.0f))

typedef __attribute__((ext_vector_type(8))) unsigned short ushort8v;
typedef float __attribute__((ext_vector_type(2))) f32x2;
typedef short __attribute__((ext_vector_type(2))) short2v;

__device__ __forceinline__ float frcp(float v){ return __builtin_amdgcn_rcpf(v); }
__device__ __forceinline__ float fexp2_(float v){ return __builtin_amdgcn_exp2f(v); }
__device__ __forceinline__ float ftanh(float x){ float e = fexp2_(x*2.8853900817779268f); return 1.0f - 2.0f*frcp(e+1.0f); }
__device__ __forceinline__ float fsigm(float x){ float e = fexp2_(x*-1.4426950408889634f); return frcp(1.0f+e); }
__device__ __forceinline__ unsigned rhu16(float x){ return (__float_as_uint(x) + 0x8000u) >> 16; }
__device__ __forceinline__ float bf2f(unsigned b){ return __uint_as_float(b << 16); }

// pack (snorm16(z) << 16) | snorm16(f) -- builtin, defined codegen (r16 verified)
__device__ __forceinline__ unsigned packzf(float f, float z){
#if __has_builtin(__builtin_amdgcn_cvt_pknorm_i16)
    const short2v p = __builtin_amdgcn_cvt_pknorm_i16(f, z);   // lo=f, hi=z
    return __builtin_bit_cast(unsigned, p);
#else
    const int zi = (int)__builtin_rintf(z * 32767.0f);
    const int fi = (int)__builtin_rintf(f * 32767.0f);
    return ((unsigned)zi << 16) | ((unsigned)fi & 0xFFFFu);
#endif
}

// ---------------- F: fused gates + scan ----------------
// Block = 16 positions x all 31 t, 256 threads.
// Phase 1 (t-parallel): thread (t = tid>>4, pos = tid&15) runs the r16 VALU
//   body (pk_fma, SGPR weights via compile-time-indexed global reads, no
//   weight LDS) for voxels t and t+16; gates -> LDS sGate[t][c^((t&1)<<3)][pos]
//   (parity swizzle: writes AND reads both exactly 2 lanes/bank = free).
// Phase 2 (after 1 barrier): thread (c = tid>>4, pos = tid&15) scans 31 steps
//   from LDS, stores h bf16 to hb in STANDARD [b][c][t][hw] layout (32B
//   segments -- r3-r8 measured no write amplification), GAP partials.
// This removes kA's 254MB gate write + kB's 260MB gate read (~80us HBM
// round-trip) and kB's launch. LDS 31.7KB -> 5 blocks/CU = 20 waves/CU.
template<bool BF16H>
__global__ __launch_bounds__(256) void kF_fused(
    const float* __restrict__ x,
    const float* __restrict__ wf1, const float* __restrict__ bf1,
    const float* __restrict__ wf2, const float* __restrict__ bf2,
    const float* __restrict__ ww1, const float* __restrict__ bw1,
    const float* __restrict__ ww2, const float* __restrict__ bw2,
    float* __restrict__ out, unsigned short* __restrict__ hb,
    float* __restrict__ partials)
{
    __shared__ unsigned int sGate[TDIM][16][16];   // [t][c-swz][pos], 31744 B

    const int tid = threadIdx.x;
    const int blk = blockIdx.x;
    const int b   = blk >> 12;                  // 4096 blocks per batch
    const int p0  = (blk & 4095) << 4;

    // ---- phase 1: gates for voxels (t, pos) and (t+16, pos) ----
    {
        const int t   = tid >> 4;               // 0..15
        const int pos = tid & 15;

        auto process = [&](int u) {             // u = timestep
            const unsigned base = (unsigned)b * BS + (unsigned)u * TS
                                + (unsigned)(p0 + pos);
            f32x2 xv2[8];
#pragma unroll
            for (int q = 0; q < 8; ++q) {
                xv2[q].x = x[base + (unsigned)(2*q)   * CS];
                xv2[q].y = x[base + (unsigned)(2*q+1) * CS];
            }
            const int csw = ((u & 1) << 3);     // c-parity swizzle for LDS

            f32x2 af2[8], aw2[8];
#pragma unroll
            for (int op = 0; op < 8; ++op) {
                const int o0 = 2 * op, o1 = 2 * op + 1;
                f32x2 a1e = {bf1[o0], 0.f}, a1o = {bf1[o1], 0.f};
                f32x2 a2e = {bw1[o0], 0.f}, a2o = {bw1[o1], 0.f};
#pragma unroll
                for (int q = 0; q < 8; ++q) {
                    a1e = __builtin_elementwise_fma(*(const f32x2*)&wf1[o0*16 + q*2], xv2[q], a1e);
                    a1o = __builtin_elementwise_fma(*(const f32x2*)&wf1[o1*16 + q*2], xv2[q], a1o);
                    a2e = __builtin_elementwise_fma(*(const f32x2*)&ww1[o0*16 + q*2], xv2[q], a2e);
                    a2o = __builtin_elementwise_fma(*(const f32x2*)&ww1[o1*16 + q*2], xv2[q], a2o);
                }
                af2[op].x = ftanh(a1e.x + a1e.y);
                af2[op].y = ftanh(a1o.x + a1o.y);
                aw2[op].x = ftanh(a2e.x + a2e.y);
                aw2[op].y = ftanh(a2o.x + a2o.y);
            }
#pragma unroll
            for (int op = 0; op < 8; ++op) {
                const int o0 = 2 * op, o1 = 2 * op + 1;
                f32x2 a1e = {bf2[o0], 0.f}, a1o = {bf2[o1], 0.f};
                f32x2 a2e = {bw2[o0], 0.f}, a2o = {bw2[o1], 0.f};
#pragma unroll
                for (int q = 0; q < 8; ++q) {
                    a1e = __builtin_elementwise_fma(*(const f32x2*)&wf2[o0*16 + q*2], af2[q], a1e);
                    a1o = __builtin_elementwise_fma(*(const f32x2*)&wf2[o1*16 + q*2], af2[q], a1o);
                    a2e = __builtin_elementwise_fma(*(const f32x2*)&ww2[o0*16 + q*2], aw2[q], a2e);
                    a2o = __builtin_elementwise_fma(*(const f32x2*)&ww2[o1*16 + q*2], aw2[q], a2o);
                }
                const float z0 = ftanh(a1e.x + a1e.y), z1 = ftanh(a1o.x + a1o.y);
                const float f0 = fsigm(a2e.x + a2e.y), f1 = fsigm(a2o.x + a2o.y);
                sGate[u][o0 ^ csw][pos] = packzf(f0, z0);
                sGate[u][o1 ^ csw][pos] = packzf(f1, z1);
            }
        };

        process(t);
        if (t + 16 < TDIM) process(t + 16);
    }
    __syncthreads();

    // ---- phase 2: scan (thread = (c, pos)) ----
    {
        const int c   = tid >> 4, pos = tid & 15;
        const unsigned obase = (unsigned)b * BS + (unsigned)c * CS
                             + (unsigned)(p0 + pos);
        float h = 0.f, s = 0.f;
#pragma unroll 1
        for (int t = 0; t < TDIM; ++t) {
            const int wd = (int)sGate[t][c ^ ((t & 1) << 3)][pos];
            const float z = (float)(wd >> 16) * (1.0f / 32767.0f);
            const float f = (float)((wd << 16) >> 16) * (1.0f / 32767.0f);
            h = fmaf(f, h - z, z);              // f*h + (1-f)*z
            s += h;
            if (BF16H) hb[obase + (unsigned)t * TS] = (unsigned short)rhu16(h);
            else       out[obase + (unsigned)t * TS] = h;
        }
#pragma unroll
        for (int off = 8; off; off >>= 1) s += __shfl_down(s, off, 16);
        if (pos == 0) partials[blk * 16 + c] = s;
    }
}

// ---------------- k2: reduce partials -> att (r7-verified layout) ----------
__global__ __launch_bounds__(1024) void k2_attention(
    const float* __restrict__ partials, const float* __restrict__ wsca,
    const float* __restrict__ bsca, float* __restrict__ att)
{
    __shared__ float red[2][16][32];
    __shared__ float gap[2][16];
    const int tid = threadIdx.x;
    {
        const int b = tid >> 9, c = (tid >> 5) & 15, seg = tid & 31;
        float s = 0.f;
        const float* p = partials + (size_t)(b * 4096 + seg * 128) * 16 + c;
        for (int j = 0; j < 128; ++j) s += p[j * 16];
        red[b][c][seg] = s;
    }
    __syncthreads();
    if (tid < 32) {
        const int b = tid >> 4, c = tid & 15;
        float s = 0.f;
#pragma unroll
        for (int g = 0; g < 32; ++g) s += red[b][c][g];
        gap[b][c] = s * GAP_INV;
    }
    __syncthreads();
    if (tid < 32) {
        const int b = tid >> 4, o = tid & 15;
        float acc = bsca[o];
#pragma unroll
        for (int c = 0; c < 16; ++c) acc = fmaf(wsca[o*16 + c], gap[b][c], acc);
        att[b*16 + o] = fsigm(acc);
    }
}

// ---------------- k3: scale ----------------
// bf16-h path: read h (bf16, ws), write fp32 out. grid (248, 32) x 1024: exact.
__global__ __launch_bounds__(1024) void k3_scale_b(
    const unsigned short* __restrict__ hb, const float* __restrict__ att,
    float* __restrict__ out)
{
    const int bc = blockIdx.y;
    const float a = att[bc];
    const unsigned i = blockIdx.x * 1024 + threadIdx.x;     // < 253,952 = CS/8
    const size_t base = (size_t)bc * CS;
    const ushort8v v = ((const ushort8v*)(hb + base))[i];
    float4 o1, o2;
    o1.x = bf2f(v[0])*a; o1.y = bf2f(v[1])*a; o1.z = bf2f(v[2])*a; o1.w = bf2f(v[3])*a;
    o2.x = bf2f(v[4])*a; o2.y = bf2f(v[5])*a; o2.z = bf2f(v[6])*a; o2.w = bf2f(v[7])*a;
    float4* op = (float4*)(out + base);
    op[i*2]     = o1;
    op[i*2 + 1] = o2;
}

// fallback: in-place fp32 scale (h already resides in d_out)
__global__ __launch_bounds__(1024) void k3_scale_a(
    const float* __restrict__ att, float* __restrict__ out)
{
    const int bc = blockIdx.y;
    const float a = att[bc];
    const unsigned i = blockIdx.x * 1024 + threadIdx.x;
    float4* op = (float4*)(out + (size_t)bc * CS);
    float4 v1 = op[i*2], v2 = op[i*2 + 1];
    v1.x *= a; v1.y *= a; v1.z *= a; v1.w *= a;
    v2.x *= a; v2.y *= a; v2.z *= a; v2.w *= a;
    op[i*2] = v1; op[i*2 + 1] = v2;
}

extern "C" void kernel_launch(void* const* d_in, const int* in_sizes, int n_in,
                              void* d_out, int out_size, void* d_ws, size_t ws_size,
                              hipStream_t stream) {
    const float* x    = (const float*)d_in[0];
    const float* wf1  = (const float*)d_in[1];
    const float* bf1  = (const float*)d_in[2];
    const float* wf2  = (const float*)d_in[3];
    const float* bf2  = (const float*)d_in[4];
    const float* ww1  = (const float*)d_in[5];
    const float* bw1  = (const float*)d_in[6];
    const float* ww2  = (const float*)d_in[7];
    const float* bw2  = (const float*)d_in[8];
    const float* wsca = (const float*)d_in[9];
    const float* bsca = (const float*)d_in[10];
    float* out = (float*)d_out;

    const size_t hbBytes   = (size_t)NTOT * 2;               // 130,023,424
    const size_t partBytes = (size_t)8192 * 16 * 4;          // 524,288
    const bool bf16h = ws_size >= hbBytes + partBytes + 256;

    unsigned short* hb = (unsigned short*)d_ws;
    float* partials = bf16h ? (float*)((char*)d_ws + hbBytes) : (float*)d_ws;
    float* att = partials + 8192 * 16;

    if (bf16h) {
        kF_fused<true><<<8192, 256, 0, stream>>>(x, wf1, bf1, wf2, bf2,
            ww1, bw1, ww2, bw2, out, hb, partials);
        k2_attention<<<1, 1024, 0, stream>>>(partials, wsca, bsca, att);
        k3_scale_b<<<dim3(248, 32), 1024, 0, stream>>>(hb, att, out);
    } else {
        kF_fused<false><<<8192, 256, 0, stream>>>(x, wf1, bf1, wf2, bf2,
            ww1, bw1, ww2, bw2, out, hb, partials);
        k2_attention<<<1, 1024, 0, stream>>>(partials, wsca, bsca, att);
        k3_scale_a<<<dim3(248, 32), 1024, 0, stream>>>(att, out);
    }
}

// Round 19
// 295.992 us; speedup vs baseline: 1.2838x; 1.2838x over previous
//
#include <hip/hip_runtime.h>
#include <hip/hip_bf16.h>

// x [B=2, C=16, T=31, H=256, W=256] fp32
#define TDIM 31
#define TS   65536                 // t stride (H*W)
#define CS   (TDIM * TS)           // c stride = 2,031,616
#define BS   (16 * CS)             // b stride
#define NTOT (2 * BS)              // 65,011,712
#define GAP_INV (1.0f / (31.0f * 65536.0f))

typedef __attribute__((ext_vector_type(8))) unsigned short ushort8v;
typedef float __attribute__((ext_vector_type(2))) f32x2;
typedef short __attribute__((ext_vector_type(2))) short2v;

__device__ __forceinline__ float frcp(float v){ return __builtin_amdgcn_rcpf(v); }
__device__ __forceinline__ float fexp2_(float v){ return __builtin_amdgcn_exp2f(v); }
__device__ __forceinline__ float ftanh(float x){ float e = fexp2_(x*2.8853900817779268f); return 1.0f - 2.0f*frcp(e+1.0f); }
__device__ __forceinline__ float fsigm(float x){ float e = fexp2_(x*-1.4426950408889634f); return frcp(1.0f+e); }
__device__ __forceinline__ unsigned rhu16(float x){ return (__float_as_uint(x) + 0x8000u) >> 16; }
__device__ __forceinline__ float bf2f(unsigned b){ return __uint_as_float(b << 16); }

// pack (snorm16(z) << 16) | snorm16(f) -- builtin, defined codegen (r16 verified)
__device__ __forceinline__ unsigned packzf(float f, float z){
#if __has_builtin(__builtin_amdgcn_cvt_pknorm_i16)
    const short2v p = __builtin_amdgcn_cvt_pknorm_i16(f, z);   // lo=f, hi=z
    return __builtin_bit_cast(unsigned, p);
#else
    const int zi = (int)__builtin_rintf(z * 32767.0f);
    const int fi = (int)__builtin_rintf(f * 32767.0f);
    return ((unsigned)zi << 16) | ((unsigned)fi & 0xFFFFu);
#endif
}

// ---------------- kA: gates (pure streaming, t-parallel) ----------------
// Measured-best structure (r16: 176us, total 299us).
// r17 lesson: fusing the scan into 16-pos blocks breaks x coalescing (64B
// segments) and costs more than the gate HBM round-trip saves (300 vs 238).
// Thread = one (b, t, pos) with 256-wide pos blocks -> fully coalesced 256B
// loads/stores. pk_fma via __builtin_elementwise_fma (SGPR-pair weights read
// at compile-time indices -> scalar pipe; no LDS). Pairwise-o loops (4 indep
// chains). 1-instruction quantize (cvt_pknorm). Writes packed gate u32 into
// gates (= d_out scratch; k3 overwrites d_out afterwards).
__global__ __launch_bounds__(256) void kA_gates(
    const float* __restrict__ x,
    const float* __restrict__ wf1, const float* __restrict__ bf1,
    const float* __restrict__ wf2, const float* __restrict__ bf2,
    const float* __restrict__ ww1, const float* __restrict__ bw1,
    const float* __restrict__ ww2, const float* __restrict__ bw2,
    unsigned int* __restrict__ gates)
{
    const int tid = threadIdx.x;
    const int pos = blockIdx.x * 256 + tid;     // 0..65535
    const int t   = blockIdx.y;                 // 0..30
    const int b   = blockIdx.z;                 // 0..1
    const unsigned base = (unsigned)b * BS + (unsigned)t * TS + (unsigned)pos;

    f32x2 xv2[8];
#pragma unroll
    for (int q = 0; q < 8; ++q) {
        xv2[q].x = x[base + (unsigned)(2*q)   * CS];
        xv2[q].y = x[base + (unsigned)(2*q+1) * CS];
    }

    // conv1 (both branches, channels in pairs) + tanh
    f32x2 af2[8], aw2[8];
#pragma unroll
    for (int op = 0; op < 8; ++op) {
        const int o0 = 2 * op, o1 = 2 * op + 1;
        f32x2 a1e = {bf1[o0], 0.f}, a1o = {bf1[o1], 0.f};
        f32x2 a2e = {bw1[o0], 0.f}, a2o = {bw1[o1], 0.f};
#pragma unroll
        for (int q = 0; q < 8; ++q) {
            a1e = __builtin_elementwise_fma(*(const f32x2*)&wf1[o0*16 + q*2], xv2[q], a1e);
            a1o = __builtin_elementwise_fma(*(const f32x2*)&wf1[o1*16 + q*2], xv2[q], a1o);
            a2e = __builtin_elementwise_fma(*(const f32x2*)&ww1[o0*16 + q*2], xv2[q], a2e);
            a2o = __builtin_elementwise_fma(*(const f32x2*)&ww1[o1*16 + q*2], xv2[q], a2o);
        }
        af2[op].x = ftanh(a1e.x + a1e.y);
        af2[op].y = ftanh(a1o.x + a1o.y);
        aw2[op].x = ftanh(a2e.x + a2e.y);
        aw2[op].y = ftanh(a2o.x + a2o.y);
    }
    // conv2 (both branches, channels in pairs) -> z=tanh, f=sigm -> pack
#pragma unroll
    for (int op = 0; op < 8; ++op) {
        const int o0 = 2 * op, o1 = 2 * op + 1;
        f32x2 a1e = {bf2[o0], 0.f}, a1o = {bf2[o1], 0.f};
        f32x2 a2e = {bw2[o0], 0.f}, a2o = {bw2[o1], 0.f};
#pragma unroll
        for (int q = 0; q < 8; ++q) {
            a1e = __builtin_elementwise_fma(*(const f32x2*)&wf2[o0*16 + q*2], af2[q], a1e);
            a1o = __builtin_elementwise_fma(*(const f32x2*)&wf2[o1*16 + q*2], af2[q], a1o);
            a2e = __builtin_elementwise_fma(*(const f32x2*)&ww2[o0*16 + q*2], aw2[q], a2e);
            a2o = __builtin_elementwise_fma(*(const f32x2*)&ww2[o1*16 + q*2], aw2[q], a2o);
        }
        const float z0 = ftanh(a1e.x + a1e.y), z1 = ftanh(a1o.x + a1o.y);
        const float f0 = fsigm(a2e.x + a2e.y), f1 = fsigm(a2o.x + a2o.y);
        gates[base + (unsigned)o0 * CS] = packzf(f0, z0);
        gates[base + (unsigned)o1 * CS] = packzf(f1, z1);
    }
}

// ---------------- kB: scan over t (pure streaming) ----------------
// Thread = one (b, c, pos). 31 independent stride-TS gate loads (pipelined),
// register h-chain, h stored bf16 to ws (or f32 in-place over gates when ws
// is too small). Wave-level GAP partial per (b,c). Decode: z,f both snorm16.
template<bool BF16H>
__global__ __launch_bounds__(256) void kB_scan(
    unsigned int* __restrict__ gates,       // also f32 h output when !BF16H
    unsigned short* __restrict__ hb,
    float* __restrict__ partials)
{
    const int pos = blockIdx.x * 256 + threadIdx.x;   // 0..65535
    const int c   = blockIdx.y;                       // 0..15
    const int b   = blockIdx.z;                       // 0..1
    const unsigned base = (unsigned)b * BS + (unsigned)c * CS + (unsigned)pos;

    float h = 0.f, s = 0.f;
#pragma unroll
    for (int t = 0; t < TDIM; ++t) {
        const int wd = (int)gates[base + (unsigned)t * TS];
        const float z = (float)(wd >> 16) * (1.0f / 32767.0f);
        const float f = (float)((wd << 16) >> 16) * (1.0f / 32767.0f);
        h = fmaf(f, h - z, z);              // f*h + (1-f)*z
        s += h;
        if (BF16H) hb[base + (unsigned)t * TS] = (unsigned short)rhu16(h);
        else       ((float*)gates)[base + (unsigned)t * TS] = h;   // in-place
    }
#pragma unroll
    for (int off = 32; off; off >>= 1) s += __shfl_down(s, off, 64);
    const int lane = threadIdx.x & 63, wv = threadIdx.x >> 6;
    if (lane == 0)
        partials[(unsigned)(b * 16 + c) * 1024 + blockIdx.x * 4 + wv] = s;
}

// ---------------- k2: reduce partials -> att ----------------
__global__ __launch_bounds__(1024) void k2_attention(
    const float* __restrict__ partials, const float* __restrict__ wsca,
    const float* __restrict__ bsca, float* __restrict__ att)
{
    __shared__ float red[32][32];
    __shared__ float gap[32];
    const int tid = threadIdx.x;
    {
        const int bc = tid >> 5, seg = tid & 31;
        float s = 0.f;
        const float* p = partials + (unsigned)bc * 1024 + seg * 32;
#pragma unroll
        for (int j = 0; j < 32; ++j) s += p[j];
        red[bc][seg] = s;
    }
    __syncthreads();
    if (tid < 32) {
        float s = 0.f;
#pragma unroll
        for (int g = 0; g < 32; ++g) s += red[tid][g];
        gap[tid] = s * GAP_INV;
    }
    __syncthreads();
    if (tid < 32) {
        const int b = tid >> 4, o = tid & 15;
        float acc = bsca[o];
#pragma unroll
        for (int c = 0; c < 16; ++c) acc = fmaf(wsca[o*16 + c], gap[b*16 + c], acc);
        att[b*16 + o] = fsigm(acc);
    }
}

// ---------------- k3: scale ----------------
// bf16-h path: read h (bf16, ws), write fp32 out. grid (248, 32) x 1024: exact.
__global__ __launch_bounds__(1024) void k3_scale_b(
    const unsigned short* __restrict__ hb, const float* __restrict__ att,
    float* __restrict__ out)
{
    const int bc = blockIdx.y;
    const float a = att[bc];
    const unsigned i = blockIdx.x * 1024 + threadIdx.x;     // < 253,952 = CS/8
    const size_t base = (size_t)bc * CS;
    const ushort8v v = ((const ushort8v*)(hb + base))[i];
    float4 o1, o2;
    o1.x = bf2f(v[0])*a; o1.y = bf2f(v[1])*a; o1.z = bf2f(v[2])*a; o1.w = bf2f(v[3])*a;
    o2.x = bf2f(v[4])*a; o2.y = bf2f(v[5])*a; o2.z = bf2f(v[6])*a; o2.w = bf2f(v[7])*a;
    float4* op = (float4*)(out + base);
    op[i*2]     = o1;
    op[i*2 + 1] = o2;
}

// fallback: in-place fp32 scale (h already resides in d_out)
__global__ __launch_bounds__(1024) void k3_scale_a(
    const float* __restrict__ att, float* __restrict__ out)
{
    const int bc = blockIdx.y;
    const float a = att[bc];
    const unsigned i = blockIdx.x * 1024 + threadIdx.x;
    float4* op = (float4*)(out + (size_t)bc * CS);
    float4 v1 = op[i*2], v2 = op[i*2 + 1];
    v1.x *= a; v1.y *= a; v1.z *= a; v1.w *= a;
    v2.x *= a; v2.y *= a; v2.z *= a; v2.w *= a;
    op[i*2] = v1; op[i*2 + 1] = v2;
}

extern "C" void kernel_launch(void* const* d_in, const int* in_sizes, int n_in,
                              void* d_out, int out_size, void* d_ws, size_t ws_size,
                              hipStream_t stream) {
    const float* x    = (const float*)d_in[0];
    const float* wf1  = (const float*)d_in[1];
    const float* bf1  = (const float*)d_in[2];
    const float* wf2  = (const float*)d_in[3];
    const float* bf2  = (const float*)d_in[4];
    const float* ww1  = (const float*)d_in[5];
    const float* bw1  = (const float*)d_in[6];
    const float* ww2  = (const float*)d_in[7];
    const float* bw2  = (const float*)d_in[8];
    const float* wsca = (const float*)d_in[9];
    const float* bsca = (const float*)d_in[10];
    float* out = (float*)d_out;

    const size_t hbBytes   = (size_t)NTOT * 2;               // 130,023,424
    const size_t partBytes = (size_t)32 * 1024 * 4;          // 131,072
    const bool bf16h = ws_size >= hbBytes + partBytes + 256;

    // d_out doubles as the gate buffer (u32 per element = exactly out_size);
    // kB consumes gates (fallback: overwrites them with f32 h); k3 then fully
    // overwrites d_out with the final scaled output.
    unsigned int* gates = (unsigned int*)d_out;
    unsigned short* hb = (unsigned short*)d_ws;
    float* partials = bf16h ? (float*)((char*)d_ws + hbBytes) : (float*)d_ws;
    float* att = partials + 32 * 1024;

    kA_gates<<<dim3(256, TDIM, 2), 256, 0, stream>>>(
        x, wf1, bf1, wf2, bf2, ww1, bw1, ww2, bw2, gates);

    if (bf16h) {
        kB_scan<true><<<dim3(256, 16, 2), 256, 0, stream>>>(gates, hb, partials);
        k2_attention<<<1, 1024, 0, stream>>>(partials, wsca, bsca, att);
        k3_scale_b<<<dim3(248, 32), 1024, 0, stream>>>(hb, att, out);
    } else {
        kB_scan<false><<<dim3(256, 16, 2), 256, 0, stream>>>(gates, hb, partials);
        k2_attention<<<1, 1024, 0, stream>>>(partials, wsca, bsca, att);
        k3_scale_a<<<dim3(248, 32), 1024, 0, stream>>>(att, out);
    }
}